// Round 4
// baseline (359.514 us; speedup 1.0000x reference)
//
#include <hip/hip_runtime.h>
#include <hip/hip_bf16.h>
#include <hip/hip_fp16.h>

#define DIM 512
#define HID 2048
#define NE 8
#define NTOK 4096

typedef _Float16 v8h __attribute__((ext_vector_type(8)));
typedef float v4f __attribute__((ext_vector_type(4)));

__device__ __forceinline__ void load16(const void* g, void* l) {
  __builtin_amdgcn_global_load_lds(
      (const __attribute__((address_space(1))) unsigned int*)g,
      (__attribute__((address_space(3))) unsigned int*)l, 16, 0, 0);
}

// tanh-form GELU: v * sigmoid(1.5957691*v + 0.07135482*v^3), |err| vs erf-GELU ~5e-4
__device__ __forceinline__ float gelu_fast(float v) {
  float v2 = v * v;
  float u = v * __builtin_fmaf(0.07135481627f, v2, 1.5957691216f);
  float t = __expf(-u);
  return v * __builtin_amdgcn_rcpf(1.0f + t);
}

// routing + x->f16 conversion + out bias-init fused: one wave per token
__global__ __launch_bounds__(256) void routing_kernel(const float* __restrict__ x,
                                                      const float* __restrict__ rw,
                                                      const float* __restrict__ rb,
                                                      const float* __restrict__ b2,
                                                      float* __restrict__ leaf,
                                                      _Float16* __restrict__ xh,
                                                      float* __restrict__ out) {
  const int lane = threadIdx.x & 63;
  const int wave = threadIdx.x >> 6;
  const int n = (blockIdx.x << 2) + wave;
  const float4* xv = (const float4*)(x + (size_t)n * DIM);
  const float4 x0 = xv[lane * 2], x1 = xv[lane * 2 + 1];
  v8h o;
  o[0] = (_Float16)x0.x; o[1] = (_Float16)x0.y; o[2] = (_Float16)x0.z; o[3] = (_Float16)x0.w;
  o[4] = (_Float16)x1.x; o[5] = (_Float16)x1.y; o[6] = (_Float16)x1.z; o[7] = (_Float16)x1.w;
  *(v8h*)(xh + (size_t)n * DIM + lane * 8) = o;
  float logits[7];
#pragma unroll
  for (int rr = 0; rr < 7; ++rr) {
    const float4* wv = (const float4*)(rw + rr * DIM);
    const float4 w0 = wv[lane * 2], w1v = wv[lane * 2 + 1];
    float s = x0.x * w0.x + x0.y * w0.y + x0.z * w0.z + x0.w * w0.w +
              x1.x * w1v.x + x1.y * w1v.y + x1.z * w1v.z + x1.w * w1v.w;
#pragma unroll
    for (int o2 = 32; o2; o2 >>= 1) s += __shfl_xor(s, o2, 64);
    logits[rr] = s + rb[rr];
  }
  // every lane computes f for eidx = lane&7 (lanes 8..63 duplicate 0..7)
  const int eidx = lane & 7;
  const float p0 = 1.f / (1.f + __expf(-logits[0]));
  float f = ((eidx >> 2) & 1) ? p0 : 1.f - p0;
  const float p1 = 1.f / (1.f + __expf(-logits[1 + (eidx >> 2)]));
  f *= ((eidx >> 1) & 1) ? p1 : 1.f - p1;
  const float p2 = 1.f / (1.f + __expf(-logits[3 + (eidx >> 1)]));
  f *= (eidx & 1) ? p2 : 1.f - p2;
  if (lane < NE) leaf[(size_t)n * NE + lane] = f;
  // out[n, lane*8 .. +7] = sum_e leaf[e] * b2[e, ...]
  float le[NE];
#pragma unroll
  for (int e = 0; e < NE; ++e) le[e] = __shfl(f, e, 64);
  float4 a0 = {0.f, 0.f, 0.f, 0.f}, a1 = {0.f, 0.f, 0.f, 0.f};
#pragma unroll
  for (int e = 0; e < NE; ++e) {
    const float4* bv = (const float4*)(b2 + (size_t)e * DIM + lane * 8);
    const float4 u0 = bv[0], u1 = bv[1];
    a0.x += le[e] * u0.x; a0.y += le[e] * u0.y; a0.z += le[e] * u0.z; a0.w += le[e] * u0.w;
    a1.x += le[e] * u1.x; a1.y += le[e] * u1.y; a1.z += le[e] * u1.z; a1.w += le[e] * u1.w;
  }
  float4* op = (float4*)(out + (size_t)n * DIM + lane * 8);
  op[0] = a0; op[1] = a1;
}

// both weight transposes in one launch. in fp32 [E][R][C] -> out f16 [E][C][R]
__global__ __launch_bounds__(256) void transpose_cvt2_kernel(const float* __restrict__ w1,
                                                             _Float16* __restrict__ w1t,
                                                             const float* __restrict__ w2,
                                                             _Float16* __restrict__ w2t) {
  int bx = blockIdx.x;
  const float* in;
  _Float16* outp;
  int R, C;
  if (bx < 4096) { in = w1; outp = w1t; R = DIM; C = HID; }
  else { bx -= 4096; in = w2; outp = w2t; R = HID; C = DIM; }
  const int e = bx >> 9;
  const int rem = bx & 511;
  const int tiles_r = R >> 6;
  const int rt = rem % tiles_r;
  const int ct = rem / tiles_r;
  const int r0 = rt << 6, c0 = ct << 5;
  const size_t ebase = (size_t)e * R * C;

  __shared__ float tile[32][65];
  const int tid = threadIdx.x;
#pragma unroll
  for (int it = 0; it < 2; ++it) {
    const int s = tid + (it << 8);
    const int row = s >> 3, cq = s & 7;
    const float4 v = *(const float4*)(in + ebase + (size_t)(r0 + row) * C + c0 + (cq << 2));
    tile[(cq << 2) + 0][row] = v.x;
    tile[(cq << 2) + 1][row] = v.y;
    tile[(cq << 2) + 2][row] = v.z;
    tile[(cq << 2) + 3][row] = v.w;
  }
  __syncthreads();
  const int c = tid >> 3, seg = tid & 7;
  v8h h;
#pragma unroll
  for (int u = 0; u < 8; ++u) h[u] = (_Float16)tile[c][(seg << 3) + u];
  *(v8h*)(outp + ebase + (size_t)(c0 + c) * R + r0 + (seg << 3)) = h;
}

// H'[e][n][h] = leaf[n,e] * gelu(X @ W1[e]^T + b1[e]); LDS double-buffered K-loop
__global__ __launch_bounds__(256) void gemm1_kernel(const _Float16* __restrict__ xh,
                                                    const _Float16* __restrict__ w1t,
                                                    const float* __restrict__ b1,
                                                    const float* __restrict__ leaf,
                                                    _Float16* __restrict__ H) {
  const int bx = blockIdx.x;
  const int e = bx & 7;                 // expert == XCD: W1t[e] L2-resident
  const int t = bx >> 3;
  const int mt = t & 31;
  const int nt = t >> 5;
  const int m0 = mt << 7, n0 = nt << 7;

  __shared__ alignas(16) _Float16 As[2 * 8192];
  __shared__ alignas(16) _Float16 Bs[2 * 8192];

  const int tid = threadIdx.x;
  const int lane = tid & 63;
  const int wave = tid >> 6;
  const int qm = wave >> 1, qn = wave & 1;
  const int r = lane & 15, q = lane >> 4;

  const _Float16* pa[4];
  const _Float16* pb[4];
  _Float16* la[4];
  _Float16* lb[4];
#pragma unroll
  for (int i = 0; i < 4; ++i) {
    const int ch = (wave << 8) + (i << 6) + lane;
    const int row = ch >> 3;
    const int c8 = (ch & 7) ^ (row & 7);
    pa[i] = xh + (size_t)(m0 + row) * DIM + (c8 << 3);
    pb[i] = w1t + ((size_t)e * HID + n0 + row) * DIM + (c8 << 3);
    la[i] = As + (size_t)ch * 8;
    lb[i] = Bs + (size_t)ch * 8;
  }
  const _Float16* fa[2][4];
  const _Float16* fb[2][4];
#pragma unroll
  for (int ks = 0; ks < 2; ++ks) {
#pragma unroll
    for (int i = 0; i < 4; ++i) {
      const int rowa = (qm << 6) + (i << 4) + r;
      fa[ks][i] = As + (rowa << 6) + ((((ks << 2) + q) ^ (rowa & 7)) << 3);
      const int rowb = (qn << 6) + (i << 4) + r;
      fb[ks][i] = Bs + (rowb << 6) + ((((ks << 2) + q) ^ (rowb & 7)) << 3);
    }
  }

  v4f acc[4][4];
#pragma unroll
  for (int i = 0; i < 4; ++i)
#pragma unroll
    for (int j = 0; j < 4; ++j) acc[i][j] = v4f{0.f, 0.f, 0.f, 0.f};

  // prologue: stage k-tile 0 into buffer 0
#pragma unroll
  for (int i = 0; i < 4; ++i) { load16(pa[i], la[i]); load16(pb[i], lb[i]); }

#pragma unroll
  for (int kk = 0; kk < 8; ++kk) {
    __syncthreads();                      // drains prefetch for tile kk
    if (kk < 7) {
      const int off = (((kk + 1) & 1) << 13);   // alt-buffer offset in halves
#pragma unroll
      for (int i = 0; i < 4; ++i) {
        load16(pa[i] + (kk + 1) * 64, la[i] + off);
        load16(pb[i] + (kk + 1) * 64, lb[i] + off);
      }
    }
    const int cp = ((kk & 1) << 13);
#pragma unroll
    for (int ks = 0; ks < 2; ++ks) {
      v8h a[4], b[4];
#pragma unroll
      for (int i = 0; i < 4; ++i) a[i] = *(const v8h*)(fa[ks][i] + cp);
#pragma unroll
      for (int j = 0; j < 4; ++j) b[j] = *(const v8h*)(fb[ks][j] + cp);
#pragma unroll
      for (int i = 0; i < 4; ++i)
#pragma unroll
        for (int j = 0; j < 4; ++j)
          acc[i][j] = __builtin_amdgcn_mfma_f32_16x16x32_f16(a[i], b[j], acc[i][j], 0, 0, 0);
    }
  }

  const float* b1e = b1 + (size_t)e * HID;
  _Float16* He = H + (size_t)e * NTOK * HID;
  float bias[4];
#pragma unroll
  for (int j = 0; j < 4; ++j) bias[j] = b1e[n0 + (qn << 6) + (j << 4) + r];
#pragma unroll
  for (int i = 0; i < 4; ++i) {
    const int rowb = m0 + (qm << 6) + (i << 4) + (q << 2);
#pragma unroll
    for (int rr = 0; rr < 4; ++rr) {
      const int row = rowb + rr;
      const float p = leaf[(size_t)row * NE + e];
      _Float16* hp = He + (size_t)row * HID + n0 + (qn << 6) + r;
#pragma unroll
      for (int j = 0; j < 4; ++j)
        hp[j << 4] = (_Float16)(p * gelu_fast(acc[i][j][rr] + bias[j]));
    }
  }
}

// out += H'[e] @ W2[e]^T, split-K by expert; LDS double-buffered K-loop
__global__ __launch_bounds__(256) void gemm2_kernel(const _Float16* __restrict__ H,
                                                    const _Float16* __restrict__ w2t,
                                                    float* __restrict__ out) {
  const int bx = blockIdx.x;
  const int e = bx & 7;                 // expert == XCD
  const int mt = (bx >> 3) & 31;
  const int dt = bx >> 8;
  const int m0 = mt << 7, d0 = dt << 7;

  __shared__ alignas(16) _Float16 As[2 * 8192];
  __shared__ alignas(16) _Float16 Bs[2 * 8192];

  const int tid = threadIdx.x;
  const int lane = tid & 63;
  const int wave = tid >> 6;
  const int qm = wave >> 1, qn = wave & 1;
  const int r = lane & 15, q = lane >> 4;

  const _Float16* pa[4];
  const _Float16* pb[4];
  _Float16* la[4];
  _Float16* lb[4];
#pragma unroll
  for (int i = 0; i < 4; ++i) {
    const int ch = (wave << 8) + (i << 6) + lane;
    const int row = ch >> 3;
    const int c8 = (ch & 7) ^ (row & 7);
    pa[i] = H + ((size_t)e * NTOK + m0 + row) * HID + (c8 << 3);
    pb[i] = w2t + ((size_t)e * DIM + d0 + row) * HID + (c8 << 3);
    la[i] = As + (size_t)ch * 8;
    lb[i] = Bs + (size_t)ch * 8;
  }
  const _Float16* fa[2][4];
  const _Float16* fb[2][4];
#pragma unroll
  for (int ks = 0; ks < 2; ++ks) {
#pragma unroll
    for (int i = 0; i < 4; ++i) {
      const int rowa = (qm << 6) + (i << 4) + r;
      fa[ks][i] = As + (rowa << 6) + ((((ks << 2) + q) ^ (rowa & 7)) << 3);
      const int rowb = (qn << 6) + (i << 4) + r;
      fb[ks][i] = Bs + (rowb << 6) + ((((ks << 2) + q) ^ (rowb & 7)) << 3);
    }
  }

  v4f acc[4][4];
#pragma unroll
  for (int i = 0; i < 4; ++i)
#pragma unroll
    for (int j = 0; j < 4; ++j) acc[i][j] = v4f{0.f, 0.f, 0.f, 0.f};

  // prologue: stage k-tile 0 into buffer 0
#pragma unroll
  for (int i = 0; i < 4; ++i) { load16(pa[i], la[i]); load16(pb[i], lb[i]); }

  for (int ko = 0; ko < 4; ++ko) {
#pragma unroll
    for (int u = 0; u < 8; ++u) {
      __syncthreads();                    // drains prefetch for current tile
      if (!(ko == 3 && u == 7)) {
        const int off = (((u + 1) & 1) << 13);
#pragma unroll
        for (int i = 0; i < 4; ++i) {
          load16(pa[i] + (u + 1) * 64, la[i] + off);   // (u+1)*128B folds to imm
          load16(pb[i] + (u + 1) * 64, lb[i] + off);
        }
      }
      const int cp = ((u & 1) << 13);
#pragma unroll
      for (int ks = 0; ks < 2; ++ks) {
        v8h a[4], b[4];
#pragma unroll
        for (int i = 0; i < 4; ++i) a[i] = *(const v8h*)(fa[ks][i] + cp);
#pragma unroll
        for (int j = 0; j < 4; ++j) b[j] = *(const v8h*)(fb[ks][j] + cp);
#pragma unroll
        for (int i = 0; i < 4; ++i)
#pragma unroll
          for (int j = 0; j < 4; ++j)
            acc[i][j] = __builtin_amdgcn_mfma_f32_16x16x32_f16(a[i], b[j], acc[i][j], 0, 0, 0);
      }
    }
#pragma unroll
    for (int i = 0; i < 4; ++i) { pa[i] += 512; pb[i] += 512; }
  }

#pragma unroll
  for (int i = 0; i < 4; ++i) {
    const int rowb = m0 + (qm << 6) + (i << 4) + (q << 2);
#pragma unroll
    for (int j = 0; j < 4; ++j) {
      const int col = d0 + (qn << 6) + (j << 4) + r;
#pragma unroll
      for (int rr = 0; rr < 4; ++rr)
        atomicAdd(out + (size_t)(rowb + rr) * DIM + col, acc[i][j][rr]);
    }
  }
}

extern "C" void kernel_launch(void* const* d_in, const int* in_sizes, int n_in,
                              void* d_out, int out_size, void* d_ws, size_t ws_size,
                              hipStream_t stream) {
  const float* x  = (const float*)d_in[0];
  const float* rw = (const float*)d_in[1];
  const float* rb = (const float*)d_in[2];
  const float* w1 = (const float*)d_in[3];
  const float* b1 = (const float*)d_in[4];
  const float* w2 = (const float*)d_in[5];
  const float* b2 = (const float*)d_in[6];
  float* out = (float*)d_out;

  char* ws = (char*)d_ws;
  const size_t xh_bytes   = (size_t)NTOK * DIM * 2;       // 4 MiB
  const size_t w1t_bytes  = (size_t)NE * HID * DIM * 2;   // 16 MiB
  const size_t w2t_bytes  = (size_t)NE * DIM * HID * 2;   // 16 MiB
  const size_t leaf_bytes = (size_t)NTOK * NE * 4;        // 128 KiB
  const size_t H_bytes    = (size_t)NE * NTOK * HID * 2;  // 128 MiB
  _Float16* xh   = (_Float16*)(ws);
  _Float16* w1t  = (_Float16*)(ws + xh_bytes);
  _Float16* w2t  = (_Float16*)(ws + xh_bytes + w1t_bytes);
  float*    leaf = (float*)(ws + xh_bytes + w1t_bytes + w2t_bytes);
  _Float16* Hbuf = (_Float16*)(ws + xh_bytes + w1t_bytes + w2t_bytes + leaf_bytes);
  if (ws_size < xh_bytes + w1t_bytes + w2t_bytes + leaf_bytes + H_bytes) return;

  routing_kernel<<<1024, 256, 0, stream>>>(x, rw, rb, b2, leaf, xh, out);
  transpose_cvt2_kernel<<<8192, 256, 0, stream>>>(w1, w1t, w2, w2t);
  gemm1_kernel<<<4096, 256, 0, stream>>>(xh, w1t, b1, leaf, Hbuf);
  gemm2_kernel<<<1024, 256, 0, stream>>>(Hbuf, w2t, out);
}

// Round 5
// 328.406 us; speedup vs baseline: 1.0947x; 1.0947x over previous
//
#include <hip/hip_runtime.h>
#include <hip/hip_bf16.h>
#include <hip/hip_fp16.h>

#define DIM 512
#define HID 2048
#define NE 8
#define NTOK 4096

typedef _Float16 v8h __attribute__((ext_vector_type(8)));
typedef float v16f __attribute__((ext_vector_type(16)));

__device__ __forceinline__ void load16(const void* g, void* l) {
  __builtin_amdgcn_global_load_lds(
      (const __attribute__((address_space(1))) unsigned int*)g,
      (__attribute__((address_space(3))) unsigned int*)l, 16, 0, 0);
}

// tanh-form GELU: v * sigmoid(1.5957691*v + 0.07135482*v^3), |err| vs erf-GELU ~5e-4
__device__ __forceinline__ float gelu_fast(float v) {
  float v2 = v * v;
  float u = v * __builtin_fmaf(0.07135481627f, v2, 1.5957691216f);
  float t = __expf(-u);
  return v * __builtin_amdgcn_rcpf(1.0f + t);
}

// Fused preamble: blocks 0..1023 do routing (+x->f16, +out bias-init);
// blocks 1024..9215 do both weight transposes (fp32 [E][R][C] -> f16 [E][C][R]).
__global__ __launch_bounds__(256) void pre_kernel(const float* __restrict__ x,
                                                  const float* __restrict__ rw,
                                                  const float* __restrict__ rb,
                                                  const float* __restrict__ b2,
                                                  const float* __restrict__ w1,
                                                  const float* __restrict__ w2,
                                                  float* __restrict__ leaf,
                                                  _Float16* __restrict__ xh,
                                                  float* __restrict__ out,
                                                  _Float16* __restrict__ w1t,
                                                  _Float16* __restrict__ w2t) {
  __shared__ float tile[32][65];
  if (blockIdx.x < 1024) {
    const int lane = threadIdx.x & 63;
    const int wave = threadIdx.x >> 6;
    const int n = (blockIdx.x << 2) + wave;
    const float4* xv = (const float4*)(x + (size_t)n * DIM);
    const float4 x0 = xv[lane * 2], x1 = xv[lane * 2 + 1];
    v8h o;
    o[0] = (_Float16)x0.x; o[1] = (_Float16)x0.y; o[2] = (_Float16)x0.z; o[3] = (_Float16)x0.w;
    o[4] = (_Float16)x1.x; o[5] = (_Float16)x1.y; o[6] = (_Float16)x1.z; o[7] = (_Float16)x1.w;
    *(v8h*)(xh + (size_t)n * DIM + lane * 8) = o;
    float logits[7];
#pragma unroll
    for (int rr = 0; rr < 7; ++rr) {
      const float4* wv = (const float4*)(rw + rr * DIM);
      const float4 w0 = wv[lane * 2], w1v = wv[lane * 2 + 1];
      float s = x0.x * w0.x + x0.y * w0.y + x0.z * w0.z + x0.w * w0.w +
                x1.x * w1v.x + x1.y * w1v.y + x1.z * w1v.z + x1.w * w1v.w;
#pragma unroll
      for (int o2 = 32; o2; o2 >>= 1) s += __shfl_xor(s, o2, 64);
      logits[rr] = s + rb[rr];
    }
    const int eidx = lane & 7;
    const float p0 = 1.f / (1.f + __expf(-logits[0]));
    float f = ((eidx >> 2) & 1) ? p0 : 1.f - p0;
    const float p1 = 1.f / (1.f + __expf(-logits[1 + (eidx >> 2)]));
    f *= ((eidx >> 1) & 1) ? p1 : 1.f - p1;
    const float p2 = 1.f / (1.f + __expf(-logits[3 + (eidx >> 1)]));
    f *= (eidx & 1) ? p2 : 1.f - p2;
    if (lane < NE) leaf[(size_t)n * NE + lane] = f;
    float le[NE];
#pragma unroll
    for (int e = 0; e < NE; ++e) le[e] = __shfl(f, e, 64);
    float4 a0 = {0.f, 0.f, 0.f, 0.f}, a1 = {0.f, 0.f, 0.f, 0.f};
#pragma unroll
    for (int e = 0; e < NE; ++e) {
      const float4* bv = (const float4*)(b2 + (size_t)e * DIM + lane * 8);
      const float4 u0 = bv[0], u1 = bv[1];
      a0.x += le[e] * u0.x; a0.y += le[e] * u0.y; a0.z += le[e] * u0.z; a0.w += le[e] * u0.w;
      a1.x += le[e] * u1.x; a1.y += le[e] * u1.y; a1.z += le[e] * u1.z; a1.w += le[e] * u1.w;
    }
    float4* op = (float4*)(out + (size_t)n * DIM + lane * 8);
    op[0] = a0; op[1] = a1;
  } else {
    int bx = blockIdx.x - 1024;
    const float* in;
    _Float16* outp;
    int R, C;
    if (bx < 4096) { in = w1; outp = w1t; R = DIM; C = HID; }
    else { bx -= 4096; in = w2; outp = w2t; R = HID; C = DIM; }
    const int e = bx >> 9;
    const int rem = bx & 511;
    const int tiles_r = R >> 6;
    const int rt = rem % tiles_r;
    const int ct = rem / tiles_r;
    const int r0 = rt << 6, c0 = ct << 5;
    const size_t ebase = (size_t)e * R * C;
    const int tid = threadIdx.x;
#pragma unroll
    for (int it = 0; it < 2; ++it) {
      const int s = tid + (it << 8);
      const int row = s >> 3, cq = s & 7;
      const float4 v = *(const float4*)(in + ebase + (size_t)(r0 + row) * C + c0 + (cq << 2));
      tile[(cq << 2) + 0][row] = v.x;
      tile[(cq << 2) + 1][row] = v.y;
      tile[(cq << 2) + 2][row] = v.z;
      tile[(cq << 2) + 3][row] = v.w;
    }
    __syncthreads();
    const int c = tid >> 3, seg = tid & 7;
    v8h hv;
#pragma unroll
    for (int u = 0; u < 8; ++u) hv[u] = (_Float16)tile[c][(seg << 3) + u];
    *(v8h*)(outp + ebase + (size_t)(c0 + c) * R + r0 + (seg << 3)) = hv;
  }
}

// H'[e][n][h] = leaf[n,e] * gelu(X @ W1[e]^T + b1[e])
// 256x128 block tile, 4 waves, 128x64 wave tile of 32x32x16 MFMA, BK=64.
__global__ __launch_bounds__(256, 2) void gemm1_kernel(const _Float16* __restrict__ xh,
                                                       const _Float16* __restrict__ w1t,
                                                       const float* __restrict__ b1,
                                                       const float* __restrict__ leaf,
                                                       _Float16* __restrict__ H) {
  const int bx = blockIdx.x;
  const int e = bx & 7;                  // expert == XCD: W1t[e] L2-resident
  const int t = bx >> 3;
  const int mt = t & 15;                 // 16 m-tiles of 256
  const int nt = t >> 4;                 // 16 n-tiles of 128
  const int m0 = mt << 8, n0 = nt << 7;

  __shared__ alignas(16) _Float16 As[256 * 64];   // 32 KiB
  __shared__ alignas(16) _Float16 Bs[128 * 64];   // 16 KiB

  const int tid = threadIdx.x;
  const int lane = tid & 63;
  const int wave = tid >> 6;
  const int wm = wave >> 1, wn = wave & 1;
  const int c = lane & 31, h2 = lane >> 5;
  const int cx = c & 7;

  // staging: A 2048 chunks (8/thread), B 1024 chunks (4/thread)
  const int strow = tid >> 3;            // 0..31
  const int c8 = (tid & 7) ^ (strow & 7);
  const _Float16* pa[8];
  const _Float16* pb[4];
  _Float16* la[8];
  _Float16* lb[4];
#pragma unroll
  for (int i = 0; i < 8; ++i) {
    pa[i] = xh + (size_t)(m0 + strow + 32 * i) * DIM + (c8 << 3);
    la[i] = As + tid * 8 + i * 2048;
  }
#pragma unroll
  for (int i = 0; i < 4; ++i) {
    pb[i] = w1t + ((size_t)e * HID + n0 + strow + 32 * i) * DIM + (c8 << 3);
    lb[i] = Bs + tid * 8 + i * 2048;
  }
  // fragment row bases (k-invariant)
  const _Float16* fA[4];
  const _Float16* fB[2];
#pragma unroll
  for (int i = 0; i < 4; ++i) fA[i] = As + ((wm << 7) + (i << 5) + c) * 64;
#pragma unroll
  for (int j = 0; j < 2; ++j) fB[j] = Bs + ((wn << 6) + (j << 5) + c) * 64;

  v16f acc[4][2];
#pragma unroll
  for (int i = 0; i < 4; ++i)
#pragma unroll
    for (int j = 0; j < 2; ++j)
      acc[i][j] = v16f{0.f,0.f,0.f,0.f,0.f,0.f,0.f,0.f,0.f,0.f,0.f,0.f,0.f,0.f,0.f,0.f};

#pragma unroll
  for (int kk = 0; kk < 8; ++kk) {       // K=512, BK=64; kk*128B folds to imm offset
#pragma unroll
    for (int i = 0; i < 8; ++i) load16(pa[i] + kk * 64, la[i]);
#pragma unroll
    for (int i = 0; i < 4; ++i) load16(pb[i] + kk * 64, lb[i]);
    __syncthreads();
#pragma unroll
    for (int ks = 0; ks < 4; ++ks) {
      const int so = ((((ks << 1) + h2) ^ cx) << 3);
      v8h a[4], b[2];
#pragma unroll
      for (int i = 0; i < 4; ++i) a[i] = *(const v8h*)(fA[i] + so);
#pragma unroll
      for (int j = 0; j < 2; ++j) b[j] = *(const v8h*)(fB[j] + so);
#pragma unroll
      for (int i = 0; i < 4; ++i)
#pragma unroll
        for (int j = 0; j < 2; ++j)
          acc[i][j] = __builtin_amdgcn_mfma_f32_32x32x16_f16(a[i], b[j], acc[i][j], 0, 0, 0);
    }
    __syncthreads();
  }

  // epilogue: C/D map col=lane&31, row=(reg&3)+8*(reg>>2)+4*(lane>>5)
  const float* b1e = b1 + (size_t)e * HID;
  _Float16* He = H + (size_t)e * NTOK * HID;
  const int colb = n0 + (wn << 6) + c;
  const float bias0 = b1e[colb];
  const float bias1 = b1e[colb + 32];
#pragma unroll
  for (int i = 0; i < 4; ++i) {
    const int rb0 = m0 + (wm << 7) + (i << 5) + (h2 << 2);
#pragma unroll
    for (int rg = 0; rg < 4; ++rg) {
#pragma unroll
      for (int rr = 0; rr < 4; ++rr) {
        const int row = rb0 + (rg << 3) + rr;
        const int reg = (rg << 2) + rr;
        const float p = leaf[(size_t)row * NE + e];
        _Float16* hp = He + (size_t)row * HID + colb;
        hp[0]  = (_Float16)(p * gelu_fast(acc[i][0][reg] + bias0));
        hp[32] = (_Float16)(p * gelu_fast(acc[i][1][reg] + bias1));
      }
    }
  }
}

// out += H'[e] @ W2[e]^T, split-K by expert; same tiling, K=2048.
__global__ __launch_bounds__(256, 2) void gemm2_kernel(const _Float16* __restrict__ H,
                                                       const _Float16* __restrict__ w2t,
                                                       float* __restrict__ out) {
  const int bx = blockIdx.x;
  const int e = bx & 7;                  // expert == XCD
  const int dt = (bx >> 3) & 3;          // dt fastest: 4 d-blocks of an m-slice co-resident
  const int mt = bx >> 5;
  const int m0 = mt << 8, d0 = dt << 7;

  __shared__ alignas(16) _Float16 As[256 * 64];
  __shared__ alignas(16) _Float16 Bs[128 * 64];

  const int tid = threadIdx.x;
  const int lane = tid & 63;
  const int wave = tid >> 6;
  const int wm = wave >> 1, wn = wave & 1;
  const int c = lane & 31, h2 = lane >> 5;
  const int cx = c & 7;

  const int strow = tid >> 3;
  const int c8 = (tid & 7) ^ (strow & 7);
  const _Float16* pa[8];
  const _Float16* pb[4];
  _Float16* la[8];
  _Float16* lb[4];
#pragma unroll
  for (int i = 0; i < 8; ++i) {
    pa[i] = H + ((size_t)e * NTOK + m0 + strow + 32 * i) * HID + (c8 << 3);
    la[i] = As + tid * 8 + i * 2048;
  }
#pragma unroll
  for (int i = 0; i < 4; ++i) {
    pb[i] = w2t + ((size_t)e * DIM + d0 + strow + 32 * i) * HID + (c8 << 3);
    lb[i] = Bs + tid * 8 + i * 2048;
  }
  const _Float16* fA[4];
  const _Float16* fB[2];
#pragma unroll
  for (int i = 0; i < 4; ++i) fA[i] = As + ((wm << 7) + (i << 5) + c) * 64;
#pragma unroll
  for (int j = 0; j < 2; ++j) fB[j] = Bs + ((wn << 6) + (j << 5) + c) * 64;

  v16f acc[4][2];
#pragma unroll
  for (int i = 0; i < 4; ++i)
#pragma unroll
    for (int j = 0; j < 2; ++j)
      acc[i][j] = v16f{0.f,0.f,0.f,0.f,0.f,0.f,0.f,0.f,0.f,0.f,0.f,0.f,0.f,0.f,0.f,0.f};

  for (int ko = 0; ko < 4; ++ko) {       // K=2048 = 4 x (8 unrolled BK=64 iters)
#pragma unroll
    for (int u = 0; u < 8; ++u) {
#pragma unroll
      for (int i = 0; i < 8; ++i) load16(pa[i] + u * 64, la[i]);
#pragma unroll
      for (int i = 0; i < 4; ++i) load16(pb[i] + u * 64, lb[i]);
      __syncthreads();
#pragma unroll
      for (int ks = 0; ks < 4; ++ks) {
        const int so = ((((ks << 1) + h2) ^ cx) << 3);
        v8h a[4], b[2];
#pragma unroll
        for (int i = 0; i < 4; ++i) a[i] = *(const v8h*)(fA[i] + so);
#pragma unroll
        for (int j = 0; j < 2; ++j) b[j] = *(const v8h*)(fB[j] + so);
#pragma unroll
        for (int i = 0; i < 4; ++i)
#pragma unroll
          for (int j = 0; j < 2; ++j)
            acc[i][j] = __builtin_amdgcn_mfma_f32_32x32x16_f16(a[i], b[j], acc[i][j], 0, 0, 0);
      }
      __syncthreads();
    }
#pragma unroll
    for (int i = 0; i < 8; ++i) pa[i] += 512;
#pragma unroll
    for (int i = 0; i < 4; ++i) pb[i] += 512;
  }

#pragma unroll
  for (int i = 0; i < 4; ++i) {
    const int rb0 = m0 + (wm << 7) + (i << 5) + (h2 << 2);
#pragma unroll
    for (int rg = 0; rg < 4; ++rg) {
#pragma unroll
      for (int rr = 0; rr < 4; ++rr) {
        const int row = rb0 + (rg << 3) + rr;
        const int reg = (rg << 2) + rr;
        float* op = out + (size_t)row * DIM + d0 + (wn << 6) + c;
        atomicAdd(op, acc[i][0][reg]);
        atomicAdd(op + 32, acc[i][1][reg]);
      }
    }
  }
}

extern "C" void kernel_launch(void* const* d_in, const int* in_sizes, int n_in,
                              void* d_out, int out_size, void* d_ws, size_t ws_size,
                              hipStream_t stream) {
  const float* x  = (const float*)d_in[0];
  const float* rw = (const float*)d_in[1];
  const float* rb = (const float*)d_in[2];
  const float* w1 = (const float*)d_in[3];
  const float* b1 = (const float*)d_in[4];
  const float* w2 = (const float*)d_in[5];
  const float* b2 = (const float*)d_in[6];
  float* out = (float*)d_out;

  char* ws = (char*)d_ws;
  const size_t xh_bytes   = (size_t)NTOK * DIM * 2;       // 4 MiB
  const size_t w1t_bytes  = (size_t)NE * HID * DIM * 2;   // 16 MiB
  const size_t w2t_bytes  = (size_t)NE * DIM * HID * 2;   // 16 MiB
  const size_t leaf_bytes = (size_t)NTOK * NE * 4;        // 128 KiB
  const size_t H_bytes    = (size_t)NE * NTOK * HID * 2;  // 128 MiB
  _Float16* xh   = (_Float16*)(ws);
  _Float16* w1t  = (_Float16*)(ws + xh_bytes);
  _Float16* w2t  = (_Float16*)(ws + xh_bytes + w1t_bytes);
  float*    leaf = (float*)(ws + xh_bytes + w1t_bytes + w2t_bytes);
  _Float16* Hbuf = (_Float16*)(ws + xh_bytes + w1t_bytes + w2t_bytes + leaf_bytes);
  if (ws_size < xh_bytes + w1t_bytes + w2t_bytes + leaf_bytes + H_bytes) return;

  pre_kernel<<<9216, 256, 0, stream>>>(x, rw, rb, b2, w1, w2, leaf, xh, out, w1t, w2t);
  gemm1_kernel<<<2048, 256, 0, stream>>>(xh, w1t, b1, leaf, Hbuf);
  gemm2_kernel<<<512, 256, 0, stream>>>(Hbuf, w2t, out);
}